// Round 1
// 875.061 us; speedup vs baseline: 1.0397x; 1.0397x over previous
//
#include <hip/hip_runtime.h>

// ---------- types ----------
typedef __bf16 bf16x8 __attribute__((ext_vector_type(8)));
typedef float f32x4 __attribute__((ext_vector_type(4)));

__device__ __forceinline__ unsigned short f32_to_bf16u(float f) {
  unsigned int u = __float_as_uint(f);
  u += 0x7fffu + ((u >> 16) & 1u);   // RNE; no NaN inputs here
  return (unsigned short)(u >> 16);
}
__device__ __forceinline__ float bf16u_to_f32(unsigned short s) {
  return __uint_as_float((unsigned int)s << 16);
}

// async global->LDS, 16B per lane. LDS dest is wave-uniform base + lane*16.
__device__ __forceinline__ void async_copy16(const void* gptr, void* lptr) {
  __builtin_amdgcn_global_load_lds(
      (__attribute__((address_space(1))) void*)(unsigned long long)gptr,
      (__attribute__((address_space(3))) void*)(unsigned long long)lptr,
      16, 0, 0);
}

// ---------- LoRA B@A precompute: Wba[li][o][c] = sum_r B[o][r]*A[r][c] ----------
__global__ __launch_bounds__(256) void lora_ba_kernel(
    const float* __restrict__ lora_a, const float* __restrict__ lora_b,
    float* __restrict__ Wba)
{
  const int bid = blockIdx.x;          // 3*1024
  const int li = bid >> 10;
  const int o = bid & 1023;
  const float* B = lora_b + li * 32768 + o * 32;
  const float* A = lora_a + li * 32768;
  const int c = threadIdx.x * 4;
  float4 acc = {0.f, 0.f, 0.f, 0.f};
#pragma unroll
  for (int r = 0; r < 32; r++) {
    const float br = B[r];
    const float4 a = *(const float4*)&A[r * 1024 + c];
    acc.x += br * a.x; acc.y += br * a.y; acc.z += br * a.z; acc.w += br * a.w;
  }
  *(float4*)&Wba[((size_t)li << 20) + o * 1024 + c] = acc;
}

// ---------- dequant all 18 weights (int4 -> bf16 [out,in]), LoRA pre-merged ----------
__global__ __launch_bounds__(256) void dequant_kernel(
    const int* __restrict__ wq4, const float* __restrict__ wnorm,
    const float* __restrict__ Wba, unsigned short* __restrict__ Wd)
{
  const int gi = blockIdx.x * 256 + threadIdx.x;   // < 18*524288
  const int w = gi >> 19;
  const int rem = gi & 524287;
  const int q = wq4[gi];
  const float norm = wnorm[(w << 8) + (rem >> 11)];
  float w0 = ((float)(q & 15) * (2.0f / 15.0f) - 1.0f) * norm;
  float w1 = ((float)(q >> 4) * (2.0f / 15.0f) - 1.0f) * norm;
  const int p = rem << 1;
  const int li = (w == 0) ? 0 : (w == 6) ? 1 : (w == 12) ? 2 : -1;
  if (li >= 0) {
    const float2 ba = *(const float2*)&Wba[((size_t)li << 20) + p];
    w0 += ba.x;
    w1 += ba.y;
  }
  const unsigned int packed =
      ((unsigned int)f32_to_bf16u(w1) << 16) | (unsigned int)f32_to_bf16u(w0);
  *(unsigned int*)&Wd[((size_t)w << 20) + p] = packed;
}

// ---------- fp32 -> bf16 cast ----------
__global__ __launch_bounds__(256) void cast_bf16_kernel(
    const float* __restrict__ x, unsigned short* __restrict__ o)
{
  const int i = blockIdx.x * 256 + threadIdx.x;
  const float4 v = ((const float4*)x)[i];
  ushort4 b;
  b.x = f32_to_bf16u(v.x);
  b.y = f32_to_bf16u(v.y);
  b.z = f32_to_bf16u(v.z);
  b.w = f32_to_bf16u(v.w);
  ((ushort4*)o)[i] = b;
}

// ---------- bf16 MFMA GEMM: C[m,n] = sum_k A[m,k]*W[n,k] ----------
// 256x256 tile, BK=64, 8 waves (2M x 4N), per-wave output 128x64.
// 8-phase pipelined K-loop (m201 template): per phase
//   { frag ds_reads | stage ONE 16KiB half-tile via global_load_lds |
//     s_barrier | lgkmcnt(0) | setprio(1) | 16x mfma_16x16x32_bf16 |
//     setprio(0) | s_barrier }
// with counted s_waitcnt vmcnt(6) ONLY at phases 3 and 7 (never 0 in the
// main loop) so 3 half-tiles (6 loads/wave) stay in flight across barriers.
// LDS 128 KiB = 2 buffers x 4 regions {A0,B0,A1,B1} x 16 KiB. Row interleave:
//   A0 holds rows {wm*128 + 0..63}, A1 {wm*128 + 64..127}  (wm = 0,1)
//   B0 holds cols {wn*64  + 0..31}, B1 {wn*64  + 32..63}   (wn = 0..3)
// so each region's LAST reader is phase {A0:p0, B0:p0, B1:p1, A1:p2} and the
// +7-half-tile staging stream overwrites it >=2 barriers after those reads
// are lgkm-drained (ledger verified per phase below).
// XOR-of-row bank swizzle applied on the GLOBAL source column (gload_lds lane
// mapping is identity), undone on ds_read -> conflict-free ds_read_b128.
template <int EPIL>
__global__ __launch_bounds__(512, 2) void gemm_bt(
    const unsigned short* __restrict__ A, const unsigned short* __restrict__ W,
    void* __restrict__ Out, const unsigned short* __restrict__ Res)
{
  constexpr int K = 1024;
  constexpr int N = 1024;
  __shared__ unsigned short lds[2][4][8192];  // 128 KiB

  const int tid = threadIdx.x;
  const int lane = tid & 63;
  const int wv = tid >> 6;
  const int wm = wv >> 2;          // 0..1
  const int wn = wv & 3;           // 0..3

  // XCD-grouped tile assignment: 256 blocks = 8 XCDs x 32; each XCD walks 8
  // consecutive mtiles x 4 ntiles so A-panels stay L2-local per XCD.
  const int bid = blockIdx.x;
  const int l = (bid & 7) * 32 + (bid >> 3);
  const int m0 = (l >> 2) << 8;
  const int n0 = (l & 3) << 8;

  const int fr = lane & 15;
  const int q = lane >> 4;
  const int fr7 = fr & 7;

  // staging source (per-thread; pre-swizzled source column)
  const int srow = tid >> 3;                    // 0..63
  const int schk = (tid & 7) ^ (srow & 7);
  const unsigned short* Asrc = A + (size_t)(m0 + srow) * K + schk * 8;
  const int nb0 = ((srow >> 5) << 6) + (srow & 31);
  const unsigned short* Wsrc = W + (size_t)(n0 + nb0) * K + schk * 8;

  // stage one 16 KiB half-tile: 512 threads x 2 x 16 B. LDS dest linear.
#define STAGE_A(mq, dbuf, kt)                                          \
  do {                                                                 \
    const unsigned short* s_ = Asrc + (size_t)(mq) * 64 * K + (kt);    \
    unsigned short* d_ = &lds[dbuf][(mq) ? 2 : 0][tid * 8];            \
    async_copy16(s_, d_);                                              \
    async_copy16(s_ + (size_t)128 * K, d_ + 4096);                     \
  } while (0)
#define STAGE_B(nq, dbuf, kt)                                          \
  do {                                                                 \
    const unsigned short* s_ = Wsrc + (size_t)(nq) * 32 * K + (kt);    \
    unsigned short* d_ = &lds[dbuf][(nq) ? 3 : 1][tid * 8];            \
    async_copy16(s_, d_);                                              \
    async_copy16(s_ + (size_t)128 * K, d_ + 4096);                     \
  } while (0)

  const int a_lane = (wm * 64 + fr) * 64;
  const int b_lane = (wn * 32 + fr) * 64;
  const int c0 = (q ^ fr7) << 3;        // k-chunk h=0 (swizzle undone)
  const int c1 = ((4 + q) ^ fr7) << 3;  // k-chunk h=1

#define LDA4(dbuf, mq)                                                               \
  do {                                                                               \
    _Pragma("unroll") for (int ri = 0; ri < 4; ++ri) {                               \
      af[ri][0] = *(const bf16x8*)&lds[dbuf][(mq) ? 2 : 0][a_lane + ri * 1024 + c0]; \
      af[ri][1] = *(const bf16x8*)&lds[dbuf][(mq) ? 2 : 0][a_lane + ri * 1024 + c1]; \
    }                                                                                \
  } while (0)
#define LDB2(dst, dbuf, nq)                                                          \
  do {                                                                               \
    _Pragma("unroll") for (int rj = 0; rj < 2; ++rj) {                               \
      dst[rj][0] = *(const bf16x8*)&lds[dbuf][(nq) ? 3 : 1][b_lane + rj * 1024 + c0];\
      dst[rj][1] = *(const bf16x8*)&lds[dbuf][(nq) ? 3 : 1][b_lane + rj * 1024 + c1];\
    }                                                                                \
  } while (0)

#define MFMA16(ib, jb, BB)                                                    \
  do {                                                                        \
    _Pragma("unroll") for (int i2 = 0; i2 < 4; ++i2)                          \
    _Pragma("unroll") for (int j2 = 0; j2 < 2; ++j2) {                        \
      acc[(ib) + i2][(jb) + j2] = __builtin_amdgcn_mfma_f32_16x16x32_bf16(    \
          af[i2][0], BB[j2][0], acc[(ib) + i2][(jb) + j2], 0, 0, 0);          \
      acc[(ib) + i2][(jb) + j2] = __builtin_amdgcn_mfma_f32_16x16x32_bf16(    \
          af[i2][1], BB[j2][1], acc[(ib) + i2][(jb) + j2], 0, 0, 0);          \
    }                                                                         \
  } while (0)

#define PHASE_MFMA(ib, jb, BB)                           \
  do {                                                   \
    __builtin_amdgcn_s_barrier();                        \
    asm volatile("s_waitcnt lgkmcnt(0)" ::: "memory");   \
    __builtin_amdgcn_s_setprio(1);                       \
    MFMA16(ib, jb, BB);                                  \
    __builtin_amdgcn_s_setprio(0);                       \
    __builtin_amdgcn_s_barrier();                        \
  } while (0)
#define PHASE_MFMA_VM(ib, jb, BB)                        \
  do {                                                   \
    __builtin_amdgcn_s_barrier();                        \
    asm volatile("s_waitcnt lgkmcnt(0)" ::: "memory");   \
    __builtin_amdgcn_s_setprio(1);                       \
    MFMA16(ib, jb, BB);                                  \
    __builtin_amdgcn_s_setprio(0);                       \
    asm volatile("s_waitcnt vmcnt(6)" ::: "memory");     \
    __builtin_amdgcn_s_barrier();                        \
  } while (0)

  f32x4 acc[8][4];
#pragma unroll
  for (int a_ = 0; a_ < 8; ++a_)
#pragma unroll
    for (int b_ = 0; b_ < 4; ++b_) acc[a_][b_] = (f32x4){0.f, 0.f, 0.f, 0.f};

  bf16x8 af[4][2], bf0[2][2], bf1[2][2];

  // ---- prologue: stage t0{A0,B0,A1,B1} + t1{A0,B0,A1} = 7 half-tiles ----
  STAGE_A(0, 0, 0);
  STAGE_B(0, 0, 0);
  STAGE_A(1, 0, 0);
  STAGE_B(1, 0, 0);
  STAGE_A(0, 1, 64);
  STAGE_B(0, 1, 64);
  STAGE_A(1, 1, 64);
  asm volatile("s_waitcnt vmcnt(6)" ::: "memory");  // t0 fully landed
  __builtin_amdgcn_s_barrier();

  // ---- main loop: 2 K-tiles (t=2it in buf0, t+1 in buf1) per iteration ----
  for (int it = 0; it < K / 128; ++it) {
    const int kb = it * 128;
    const int k2 = (kb + 128 < K) ? (kb + 128) : (K - 64);  // tail: harmless re-stage
    const int k3 = (kb + 192 < K) ? (kb + 192) : (K - 64);

    // p0: tile t quad(mq0,nq0); stage (t+1).B1 -> buf1 (B1 of buf1 last read prev p5)
    LDA4(0, 0);
    LDB2(bf0, 0, 0);
    STAGE_B(1, 1, kb + 64);
    PHASE_MFMA(0, 0, bf0);
    // p1: quad(mq0,nq1); stage (t+2).A0 -> buf0 (A0 last read p0, drained)
    LDB2(bf1, 0, 1);
    STAGE_A(0, 0, k2);
    PHASE_MFMA(0, 2, bf1);
    // p2: quad(mq1,nq0); stage (t+2).B0 -> buf0 (B0 last read p0)
    LDA4(0, 1);
    STAGE_B(0, 0, k2);
    PHASE_MFMA(4, 0, bf0);
    // p3: quad(mq1,nq1); stage (t+2).A1 -> buf0 (A1 last read p2); counted drain:
    //     vmcnt(6) leaves {t+2 A0,B0,A1} in flight => all of t+1 landed for p4.
    STAGE_A(1, 0, k2);
    PHASE_MFMA_VM(4, 2, bf1);
    // p4: tile t+1 quad(mq0,nq0); stage (t+2).B1 -> buf0 (B1 last read p1)
    LDA4(1, 0);
    LDB2(bf0, 1, 0);
    STAGE_B(1, 0, k2);
    PHASE_MFMA(0, 0, bf0);
    // p5: quad(mq0,nq1); stage (t+3).A0 -> buf1 (A0 last read p4)
    LDB2(bf1, 1, 1);
    STAGE_A(0, 1, k3);
    PHASE_MFMA(0, 2, bf1);
    // p6: quad(mq1,nq0); stage (t+3).B0 -> buf1 (B0 last read p4)
    LDA4(1, 1);
    STAGE_B(0, 1, k3);
    PHASE_MFMA(4, 0, bf0);
    // p7: quad(mq1,nq1); stage (t+3).A1 -> buf1 (A1 last read p6); vmcnt(6)
    //     leaves {t+3 A0,B0,A1} in flight => all of t+2 landed for next p0.
    STAGE_A(1, 1, k3);
    PHASE_MFMA_VM(4, 2, bf1);
  }

  // ---- epilogue: direct store. C/D layout: n = lane&15, m = (lane>>4)*4+reg ----
  const int mb = m0 + wm * 128 + q * 4;
  const int nb = n0 + wn * 64 + fr;
#pragma unroll
  for (int i2 = 0; i2 < 8; ++i2) {
#pragma unroll
    for (int r = 0; r < 4; ++r) {
      const int m = mb + i2 * 16 + r;
#pragma unroll
      for (int j2 = 0; j2 < 4; ++j2) {
        const int n = nb + j2 * 16;
        float v = acc[i2][j2][r];
        if (EPIL == 0) {
          v = v > 0.f ? v : 0.f;
          ((unsigned short*)Out)[(size_t)m * N + n] = f32_to_bf16u(v);
        } else if (EPIL == 1) {
          v += bf16u_to_f32(Res[(size_t)m * N + n]);
          ((unsigned short*)Out)[(size_t)m * N + n] = f32_to_bf16u(v);
        } else {
          v += bf16u_to_f32(Res[(size_t)m * N + n]);
          ((float*)Out)[(size_t)m * N + n] = v;
        }
      }
    }
  }
#undef STAGE_A
#undef STAGE_B
#undef LDA4
#undef LDB2
#undef MFMA16
#undef PHASE_MFMA
#undef PHASE_MFMA_VM
}

// ---------- LayerNorm (bf16 in s, bf16 out h) ----------
__global__ __launch_bounds__(256) void ln_kernel(
    const unsigned short* __restrict__ s_bf, const float* __restrict__ gamma,
    const float* __restrict__ beta, unsigned short* __restrict__ h_bf)
{
  const int row = blockIdx.x;
  const int tid = threadIdx.x;
  const size_t base = (size_t)row * 1024;
  const ushort4 u = ((const ushort4*)(s_bf + base))[tid];
  float v0 = bf16u_to_f32(u.x), v1 = bf16u_to_f32(u.y);
  float v2 = bf16u_to_f32(u.z), v3 = bf16u_to_f32(u.w);
  float s = v0 + v1 + v2 + v3;
  float s2 = v0 * v0 + v1 * v1 + v2 * v2 + v3 * v3;
#pragma unroll
  for (int off = 32; off > 0; off >>= 1) {
    s += __shfl_down(s, off, 64);
    s2 += __shfl_down(s2, off, 64);
  }
  __shared__ float red[8];
  if ((tid & 63) == 0) {
    red[tid >> 6] = s;
    red[4 + (tid >> 6)] = s2;
  }
  __syncthreads();
  s = red[0] + red[1] + red[2] + red[3];
  s2 = red[4] + red[5] + red[6] + red[7];
  const float mu = s * (1.0f / 1024.0f);
  const float var = s2 * (1.0f / 1024.0f) - mu * mu;
  const float rs = rsqrtf(var + 1e-5f);
  const float4 g = ((const float4*)gamma)[tid];
  const float4 bb = ((const float4*)beta)[tid];
  ushort4 ob;
  ob.x = f32_to_bf16u((v0 - mu) * rs * g.x + bb.x);
  ob.y = f32_to_bf16u((v1 - mu) * rs * g.y + bb.y);
  ob.z = f32_to_bf16u((v2 - mu) * rs * g.z + bb.z);
  ob.w = f32_to_bf16u((v3 - mu) * rs * g.w + bb.w);
  ((ushort4*)(h_bf + base))[tid] = ob;
}

// ---------- launch ----------
extern "C" void kernel_launch(void* const* d_in, const int* in_sizes, int n_in,
                              void* d_out, int out_size, void* d_ws, size_t ws_size,
                              hipStream_t stream)
{
  const float* x = (const float*)d_in[0];
  const int* wq4 = (const int*)d_in[1];
  const float* wnorm = (const float*)d_in[2];
  const float* lora_a = (const float*)d_in[3];
  const float* lora_b = (const float*)d_in[4];
  const float* ln_g = (const float*)d_in[5];
  const float* ln_b = (const float*)d_in[6];
  float* out = (float*)d_out;

  char* ws = (char*)d_ws;
  unsigned short* Wd   = (unsigned short*)(ws);              // 36 MiB
  unsigned short* x_bf = (unsigned short*)(ws + 37748736);   // 32 MiB
  unsigned short* t1   = (unsigned short*)(ws + 71303168);   // 32 MiB
  unsigned short* t2   = (unsigned short*)(ws + 104857600);  // 32 MiB
  unsigned short* s_bf = (unsigned short*)(ws + 138412032);  // 32 MiB
  unsigned short* h_bf = (unsigned short*)(ws + 171966464);  // 32 MiB
  // Wba aliases s_bf: only live during dequant, before first EPIL1 write.
  float* Wba           = (float*)(ws + 138412032);           // 12 MiB used

  lora_ba_kernel<<<3072, 256, 0, stream>>>(lora_a, lora_b, Wba);
  dequant_kernel<<<36864, 256, 0, stream>>>(wq4, wnorm, Wba, Wd);
  cast_bf16_kernel<<<16384, 256, 0, stream>>>(x, x_bf);

  const unsigned short* hb = x_bf;
  const unsigned short* hres = x_bf;
  for (int b = 0; b < 6; b++) {
    const unsigned short* W0 = Wd + (size_t)(3 * b + 0) * 1048576;
    const unsigned short* W1 = Wd + (size_t)(3 * b + 1) * 1048576;
    const unsigned short* W2 = Wd + (size_t)(3 * b + 2) * 1048576;
    gemm_bt<0><<<256, 512, 0, stream>>>(hb, W0, t1, nullptr);
    gemm_bt<0><<<256, 512, 0, stream>>>(t1, W1, t2, nullptr);
    if (b < 5) {
      gemm_bt<1><<<256, 512, 0, stream>>>(t2, W2, s_bf, hres);
      ln_kernel<<<16384, 256, 0, stream>>>(s_bf, ln_g + b * 1024, ln_b + b * 1024, h_bf);
      hb = h_bf;
      hres = h_bf;
    } else {
      gemm_bt<2><<<256, 512, 0, stream>>>(t2, W2, out, hres);
    }
  }
  (void)in_sizes; (void)n_in; (void)out_size; (void)ws_size;
}